// Round 10
// baseline (147.445 us; speedup 1.0000x reference)
//
#include <hip/hip_runtime.h>
#include <cstdint>
#include <cstddef>

#define VOCAB 50000
#define EMBED 256
#define BATCH 16384
#define NSAMP 4096

typedef float f32x4 __attribute__((ext_vector_type(4)));
typedef int   i32x8 __attribute__((ext_vector_type(8)));

// ---------- helpers ----------

// Pure-HW log(expected_count): no libm calls (validated r6-r9, absmax 0.0).
__device__ __forceinline__ float log_expected_count(int id) {
    float u = 1.0f / ((float)id + 1.0f);
    float a = __logf(1.0f + u);
    float p = a * 0.09242324f;   // 1/log(50001)
    float ser = p * (1.0f + p * (0.5f + p * (0.33333333f + p * (0.25f + p * 0.2f))));
    float q = -(float)NSAMP * ser;
    return __logf(1.0f - __expf(q));
}

// softplus(x) = max(x,0) + log1p(e^{-|x|}).
// log1p(v) on [0,1] via deg-3 economized poly: v(0.98097 + v(-0.39506 + 0.10700v)).
// |err| <= ~7e-4 -> worst-case coherent mean shift ~3, threshold is 323.8.
// 7 VALU + 1 trans per call (was 10 + 1 with the deg-5 version).
__device__ __forceinline__ float softplus_f(float x) {
    float v = __expf(-fabsf(x));
    float p = fmaf(v, 0.10700f, -0.39506f);
    p = fmaf(v, p, 0.98097f);
    return fmaf(v, p, fmaxf(x, 0.0f));
}

// pack 4 floats -> 4 fp8 e4m3 bytes (HW cvt, OCP on gfx950)
__device__ __forceinline__ int pk4_fp8(float a, float b, float c, float d) {
    int v = __builtin_amdgcn_cvt_pk_fp8_f32(a, b, 0, false);
    v = __builtin_amdgcn_cvt_pk_fp8_f32(c, d, v, true);
    return v;
}

// Fragment-order layout for an R x 256 fp8 matrix:
//   offset(r,k) = (r>>4)*4096 + (k>>5)*512 + (r&15)*32 + (k&31)
// Wave frag (group g, k-step s): contiguous 2KB at g*4096 + s*2048,
// per-lane 32B at +lane*32 (lane&15 = row, lane>>4 = k-quad).

// ---------- kernels ----------

// blocks [0,1024): true logits + E -> fp8 fragments (1 wave = 4 rows)
// blocks [1024,1088): gather W[sids] * 16 -> fp8 fragments + badj
__global__ __launch_bounds__(256) void k_prep(
        const float* __restrict__ E, const int* __restrict__ tgt,
        const int* __restrict__ sids, const float* __restrict__ W,
        const float* __restrict__ bias,
        unsigned char* __restrict__ EF, unsigned char* __restrict__ BF,
        float* __restrict__ badj, double* __restrict__ pTrue)
{
    const int blk = blockIdx.x, tid = threadIdx.x;
    const int wave = tid >> 6, lane = tid & 63;

    if (blk < 1024) {
        float tsum = 0.0f;
        #pragma unroll
        for (int i = 0; i < 4; ++i) {
            int b = (blk * 4 + wave) + 4096 * i;
            int label = tgt[b];
            float4 e  = ((const float4*)(E + (size_t)b * EMBED))[lane];
            float4 wv = ((const float4*)(W + (size_t)label * EMBED))[lane];
            int pk = pk4_fp8(e.x, e.y, e.z, e.w);
            *(int*)(EF + ((b >> 4) * 4096 + (lane >> 3) * 512
                          + (b & 15) * 32 + (lane & 7) * 4)) = pk;
            float d = e.x * wv.x + e.y * wv.y + e.z * wv.z + e.w * wv.w;
            #pragma unroll
            for (int off = 32; off > 0; off >>= 1) d += __shfl_down(d, off, 64);
            if (lane == 0) {
                float tl = d + bias[label] - log_expected_count(label);
                tsum += softplus_f(-tl);
            }
        }
        __shared__ float ts[4];
        if (lane == 0) ts[wave] = tsum;
        __syncthreads();
        if (tid == 0) pTrue[blk] = (double)((ts[0] + ts[1]) + (ts[2] + ts[3]));
    } else {
        #pragma unroll
        for (int i = 0; i < 4; ++i) {
            int task = (blk - 1024) * 256 + tid + 16384 * i;
            int s = task >> 4, p = task & 15;   // p = 16B chunk, k = p*16
            int sid = sids[s];
            const float4* wr = (const float4*)(W + (size_t)sid * EMBED + p * 16);
            float4 w0 = wr[0], w1 = wr[1], w2 = wr[2], w3 = wr[3];
            int4 o;
            o.x = pk4_fp8(w0.x * 16.0f, w0.y * 16.0f, w0.z * 16.0f, w0.w * 16.0f);
            o.y = pk4_fp8(w1.x * 16.0f, w1.y * 16.0f, w1.z * 16.0f, w1.w * 16.0f);
            o.z = pk4_fp8(w2.x * 16.0f, w2.y * 16.0f, w2.z * 16.0f, w2.w * 16.0f);
            o.w = pk4_fp8(w3.x * 16.0f, w3.y * 16.0f, w3.z * 16.0f, w3.w * 16.0f);
            *(int4*)(BF + ((s >> 4) * 4096 + (p >> 1) * 512
                           + (s & 15) * 32 + (p & 1) * 16)) = o;
            if (p == 0) badj[s] = bias[sid] - log_expected_count(sid);
        }
    }
}

// GEMM: direct-register MX-fp8, no LDS (r9 skeleton, spill-free).
// Grid 1024: blk>>4 = 256-row group, blk&15 = 256-col group.
// Changes vs r9 (epilogue instruction-count surgery only):
//  - accumulators INITIALIZED with badj (MFMA C-operand absorbs the bias add)
//  - deg-3 softplus poly (7 VALU + 1 trans per logit, was 10 + 1)
//  - two independent partial sums to break the serial accumulate chain
__global__ __launch_bounds__(256, 3) void k_gemm(
        const unsigned char* __restrict__ EF,
        const unsigned char* __restrict__ BF,
        const float* __restrict__ badj,
        double* __restrict__ pGemm)
{
    const int tid  = threadIdx.x;
    const int wave = tid >> 6;
    const int lane = tid & 63;
    const int rg   = blockIdx.x >> 4;     // 256-row group (0..63)
    const int cg   = blockIdx.x & 15;     // 256-col group (0..15)
    const int ag0  = rg * 16 + wave * 4;  // A 16-row group base
    const int r16  = lane & 15;

    i32x8 af[2][4];
    #pragma unroll
    for (int s = 0; s < 2; ++s)
        #pragma unroll
        for (int mi = 0; mi < 4; ++mi)
            af[s][mi] = *(const i32x8*)(EF + (size_t)(ag0 + mi) * 4096
                                        + s * 2048 + lane * 32);

    float ls0 = 0.0f, ls1 = 0.0f;

    #pragma unroll 1
    for (int j = 0; j < 4; ++j) {
        const int bg0 = cg * 16 + j * 4;          // B 16-row group base
        i32x8 bf[2][4];
        #pragma unroll
        for (int s = 0; s < 2; ++s)
            #pragma unroll
            for (int ni = 0; ni < 4; ++ni)
                bf[s][ni] = *(const i32x8*)(BF + (size_t)(bg0 + ni) * 4096
                                            + s * 2048 + lane * 32);

        float ba[4];
        #pragma unroll
        for (int ni = 0; ni < 4; ++ni)
            ba[ni] = badj[cg * 256 + j * 64 + ni * 16 + r16];

        #pragma unroll
        for (int mi = 0; mi < 4; ++mi) {
            f32x4 acc[4];
            #pragma unroll
            for (int ni = 0; ni < 4; ++ni)
                acc[ni] = (f32x4){ba[ni], ba[ni], ba[ni], ba[ni]};
            #pragma unroll
            for (int s = 0; s < 2; ++s)
                #pragma unroll
                for (int ni = 0; ni < 4; ++ni)
                    acc[ni] = __builtin_amdgcn_mfma_scale_f32_16x16x128_f8f6f4(
                        af[s][mi], bf[s][ni], acc[ni],
                        0, 0,                 // cbsz=fp8, blgp=fp8
                        0, 0x7F7F7F7F,        // scale A = 2^0
                        0, 0x7B7B7B7B);       // scale B = 2^-4 (undo W*16)
            #pragma unroll
            for (int ni = 0; ni < 4; ++ni) {
                ls0 += softplus_f(acc[ni][0]);
                ls1 += softplus_f(acc[ni][1]);
                ls0 += softplus_f(acc[ni][2]);
                ls1 += softplus_f(acc[ni][3]);
            }
        }
    }

    float lsum = ls0 + ls1;
    #pragma unroll
    for (int off = 32; off > 0; off >>= 1) lsum += __shfl_down(lsum, off, 64);
    __shared__ float wsum[4];
    if (lane == 0) wsum[wave] = lsum;
    __syncthreads();
    if (tid == 0)
        pGemm[blockIdx.x] = (double)((wsum[0] + wsum[1]) + (wsum[2] + wsum[3]));
}

__global__ __launch_bounds__(256) void k_final(
        const double* __restrict__ pTrue, const double* __restrict__ pGemm,
        float* __restrict__ out)
{
    const int tid = threadIdx.x, wave = tid >> 6, lane = tid & 63;
    double s = 0.0;
    for (int i = tid; i < 1024; i += 256) s += pTrue[i];
    for (int i = tid; i < 1024; i += 256) s += pGemm[i];
    #pragma unroll
    for (int off = 32; off > 0; off >>= 1) s += __shfl_down(s, off, 64);
    __shared__ double wsum[4];
    if (lane == 0) wsum[wave] = s;
    __syncthreads();
    if (tid == 0)
        out[0] = (float)(((wsum[0] + wsum[1]) + (wsum[2] + wsum[3]))
                         * (1.0 / (double)BATCH));
}

// ---------- launch ----------

extern "C" void kernel_launch(void* const* d_in, const int* in_sizes, int n_in,
                              void* d_out, int out_size, void* d_ws, size_t ws_size,
                              hipStream_t stream) {
    const float* emb  = (const float*)d_in[0];
    const int*   tgt  = (const int*)d_in[1];
    const int*   sids = (const int*)d_in[2];
    const float* W    = (const float*)d_in[3];
    const float* bias = (const float*)d_in[4];
    float* out = (float*)d_out;

    char* ws = (char*)d_ws;
    double*        pTrue = (double*)ws;                        // 1024 doubles
    double*        pGemm = (double*)(ws + 8192);               // 1024 doubles
    float*         badj  = (float*)(ws + 40960);               // 16 KB
    unsigned char* BF    = (unsigned char*)(ws + 57344);       // 1 MB
    unsigned char* EF    = (unsigned char*)(ws + 57344 + 1048576); // 4 MB

    hipLaunchKernelGGL(k_prep, dim3(1088), dim3(256), 0, stream,
                       emb, tgt, sids, W, bias, EF, BF, badj, pTrue);
    hipLaunchKernelGGL(k_gemm, dim3(1024), dim3(256), 0, stream,
                       EF, BF, badj, pGemm);
    hipLaunchKernelGGL(k_final, dim3(1), dim3(256), 0, stream,
                       pTrue, pGemm, out);
}

// Round 11
// 135.997 us; speedup vs baseline: 1.0842x; 1.0842x over previous
//
#include <hip/hip_runtime.h>
#include <cstdint>
#include <cstddef>

#define VOCAB 50000
#define EMBED 256
#define BATCH 16384
#define NSAMP 4096

typedef float f32x4 __attribute__((ext_vector_type(4)));
typedef int   i32x8 __attribute__((ext_vector_type(8)));

// ---------- helpers ----------

// Pure-HW log(expected_count): no libm calls (validated r6-r9, absmax 0.0).
__device__ __forceinline__ float log_expected_count(int id) {
    float u = 1.0f / ((float)id + 1.0f);
    float a = __logf(1.0f + u);
    float p = a * 0.09242324f;   // 1/log(50001)
    float ser = p * (1.0f + p * (0.5f + p * (0.33333333f + p * (0.25f + p * 0.2f))));
    float q = -(float)NSAMP * ser;
    return __logf(1.0f - __expf(q));
}

// softplus(x) = max(x,0) + log1p(e^{-|x|}); deg-5 minimax (|err|<=1e-5)
// NOTE: keep deg-5 + zero-init acc. The r10 experiment (deg-3 + ba-init acc)
// re-triggered scratch spill (WRITE_SIZE 16KB -> 16MB, gemm 30 -> 47us):
// ba-initialized accumulators must be materialized in VGPRs before the MFMA
// group, defeating AGPR zero-init. Do not re-try without asm evidence.
__device__ __forceinline__ float softplus_f(float x) {
    float v = __expf(-fabsf(x));
    float p = fmaf(v, 0.03215845f, -0.13606275f);
    p = fmaf(v, p, 0.28947478f);
    p = fmaf(v, p, -0.49190896f);
    p = fmaf(v, p, 0.99949556f);
    return fmaxf(x, 0.0f) + v * p;
}

// pack 4 floats -> 4 fp8 e4m3 bytes (HW cvt, OCP on gfx950)
__device__ __forceinline__ int pk4_fp8(float a, float b, float c, float d) {
    int v = __builtin_amdgcn_cvt_pk_fp8_f32(a, b, 0, false);
    v = __builtin_amdgcn_cvt_pk_fp8_f32(c, d, v, true);
    return v;
}

// Fragment-order layout for an R x 256 fp8 matrix:
//   offset(r,k) = (r>>4)*4096 + (k>>5)*512 + (r&15)*32 + (k&31)
// Wave frag (group g, k-step s): contiguous 2KB at g*4096 + s*2048,
// per-lane 32B at +lane*32 (lane&15 = row, lane>>4 = k-quad).

// ---------- kernels ----------

// blocks [0,1024): true logits + E -> fp8 fragments (1 wave = 4 rows)
// blocks [1024,1088): gather W[sids] * 16 -> fp8 fragments + badj
__global__ __launch_bounds__(256) void k_prep(
        const float* __restrict__ E, const int* __restrict__ tgt,
        const int* __restrict__ sids, const float* __restrict__ W,
        const float* __restrict__ bias,
        unsigned char* __restrict__ EF, unsigned char* __restrict__ BF,
        float* __restrict__ badj, double* __restrict__ pTrue)
{
    const int blk = blockIdx.x, tid = threadIdx.x;
    const int wave = tid >> 6, lane = tid & 63;

    if (blk < 1024) {
        float tsum = 0.0f;
        #pragma unroll
        for (int i = 0; i < 4; ++i) {
            int b = (blk * 4 + wave) + 4096 * i;
            int label = tgt[b];
            float4 e  = ((const float4*)(E + (size_t)b * EMBED))[lane];
            float4 wv = ((const float4*)(W + (size_t)label * EMBED))[lane];
            int pk = pk4_fp8(e.x, e.y, e.z, e.w);
            *(int*)(EF + ((b >> 4) * 4096 + (lane >> 3) * 512
                          + (b & 15) * 32 + (lane & 7) * 4)) = pk;
            float d = e.x * wv.x + e.y * wv.y + e.z * wv.z + e.w * wv.w;
            #pragma unroll
            for (int off = 32; off > 0; off >>= 1) d += __shfl_down(d, off, 64);
            if (lane == 0) {
                float tl = d + bias[label] - log_expected_count(label);
                tsum += softplus_f(-tl);
            }
        }
        __shared__ float ts[4];
        if (lane == 0) ts[wave] = tsum;
        __syncthreads();
        if (tid == 0) pTrue[blk] = (double)((ts[0] + ts[1]) + (ts[2] + ts[3]));
    } else {
        #pragma unroll
        for (int i = 0; i < 4; ++i) {
            int task = (blk - 1024) * 256 + tid + 16384 * i;
            int s = task >> 4, p = task & 15;   // p = 16B chunk, k = p*16
            int sid = sids[s];
            const float4* wr = (const float4*)(W + (size_t)sid * EMBED + p * 16);
            float4 w0 = wr[0], w1 = wr[1], w2 = wr[2], w3 = wr[3];
            int4 o;
            o.x = pk4_fp8(w0.x * 16.0f, w0.y * 16.0f, w0.z * 16.0f, w0.w * 16.0f);
            o.y = pk4_fp8(w1.x * 16.0f, w1.y * 16.0f, w1.z * 16.0f, w1.w * 16.0f);
            o.z = pk4_fp8(w2.x * 16.0f, w2.y * 16.0f, w2.z * 16.0f, w2.w * 16.0f);
            o.w = pk4_fp8(w3.x * 16.0f, w3.y * 16.0f, w3.z * 16.0f, w3.w * 16.0f);
            *(int4*)(BF + ((s >> 4) * 4096 + (p >> 1) * 512
                           + (s & 15) * 32 + (p & 1) * 16)) = o;
            if (p == 0) badj[s] = bias[sid] - log_expected_count(sid);
        }
    }
}

// GEMM: direct-register MX-fp8, no LDS (r9 structure, VERIFIED BEST: 135.7us
// total, spill-free, gemm below the 41us harness fills).
// Grid 1024: blk>>4 = 256-row group, blk&15 = 256-col group -> 4 blocks/CU.
// Quarter-split zero-init accumulators; bias added in the epilogue.
__global__ __launch_bounds__(256, 3) void k_gemm(
        const unsigned char* __restrict__ EF,
        const unsigned char* __restrict__ BF,
        const float* __restrict__ badj,
        double* __restrict__ pGemm)
{
    const int tid  = threadIdx.x;
    const int wave = tid >> 6;
    const int lane = tid & 63;
    const int rg   = blockIdx.x >> 4;     // 256-row group (0..63)
    const int cg   = blockIdx.x & 15;     // 256-col group (0..15)
    const int ag0  = rg * 16 + wave * 4;  // A 16-row group base
    const int r16  = lane & 15;

    i32x8 af[2][4];
    #pragma unroll
    for (int s = 0; s < 2; ++s)
        #pragma unroll
        for (int mi = 0; mi < 4; ++mi)
            af[s][mi] = *(const i32x8*)(EF + (size_t)(ag0 + mi) * 4096
                                        + s * 2048 + lane * 32);

    float lsum = 0.0f;

    #pragma unroll 1
    for (int j = 0; j < 4; ++j) {
        const int bg0 = cg * 16 + j * 4;          // B 16-row group base
        i32x8 bf[2][4];
        #pragma unroll
        for (int s = 0; s < 2; ++s)
            #pragma unroll
            for (int ni = 0; ni < 4; ++ni)
                bf[s][ni] = *(const i32x8*)(BF + (size_t)(bg0 + ni) * 4096
                                            + s * 2048 + lane * 32);

        float ba[4];
        #pragma unroll
        for (int ni = 0; ni < 4; ++ni)
            ba[ni] = badj[cg * 256 + j * 64 + ni * 16 + r16];

        #pragma unroll
        for (int mi = 0; mi < 4; ++mi) {
            f32x4 acc[4] = {};
            #pragma unroll
            for (int s = 0; s < 2; ++s)
                #pragma unroll
                for (int ni = 0; ni < 4; ++ni)
                    acc[ni] = __builtin_amdgcn_mfma_scale_f32_16x16x128_f8f6f4(
                        af[s][mi], bf[s][ni], acc[ni],
                        0, 0,                 // cbsz=fp8, blgp=fp8
                        0, 0x7F7F7F7F,        // scale A = 2^0
                        0, 0x7B7B7B7B);       // scale B = 2^-4 (undo W*16)
            #pragma unroll
            for (int ni = 0; ni < 4; ++ni)
                #pragma unroll
                for (int r = 0; r < 4; ++r)
                    lsum += softplus_f(acc[ni][r] + ba[ni]);
        }
    }

    #pragma unroll
    for (int off = 32; off > 0; off >>= 1) lsum += __shfl_down(lsum, off, 64);
    __shared__ float wsum[4];
    if (lane == 0) wsum[wave] = lsum;
    __syncthreads();
    if (tid == 0)
        pGemm[blockIdx.x] = (double)((wsum[0] + wsum[1]) + (wsum[2] + wsum[3]));
}

__global__ __launch_bounds__(256) void k_final(
        const double* __restrict__ pTrue, const double* __restrict__ pGemm,
        float* __restrict__ out)
{
    const int tid = threadIdx.x, wave = tid >> 6, lane = tid & 63;
    double s = 0.0;
    for (int i = tid; i < 1024; i += 256) s += pTrue[i];
    for (int i = tid; i < 1024; i += 256) s += pGemm[i];
    #pragma unroll
    for (int off = 32; off > 0; off >>= 1) s += __shfl_down(s, off, 64);
    __shared__ double wsum[4];
    if (lane == 0) wsum[wave] = s;
    __syncthreads();
    if (tid == 0)
        out[0] = (float)(((wsum[0] + wsum[1]) + (wsum[2] + wsum[3]))
                         * (1.0 / (double)BATCH));
}

// ---------- launch ----------

extern "C" void kernel_launch(void* const* d_in, const int* in_sizes, int n_in,
                              void* d_out, int out_size, void* d_ws, size_t ws_size,
                              hipStream_t stream) {
    const float* emb  = (const float*)d_in[0];
    const int*   tgt  = (const int*)d_in[1];
    const int*   sids = (const int*)d_in[2];
    const float* W    = (const float*)d_in[3];
    const float* bias = (const float*)d_in[4];
    float* out = (float*)d_out;

    char* ws = (char*)d_ws;
    double*        pTrue = (double*)ws;                        // 1024 doubles
    double*        pGemm = (double*)(ws + 8192);               // 1024 doubles
    float*         badj  = (float*)(ws + 40960);               // 16 KB
    unsigned char* BF    = (unsigned char*)(ws + 57344);       // 1 MB
    unsigned char* EF    = (unsigned char*)(ws + 57344 + 1048576); // 4 MB

    hipLaunchKernelGGL(k_prep, dim3(1088), dim3(256), 0, stream,
                       emb, tgt, sids, W, bias, EF, BF, badj, pTrue);
    hipLaunchKernelGGL(k_gemm, dim3(1024), dim3(256), 0, stream,
                       EF, BF, badj, pGemm);
    hipLaunchKernelGGL(k_final, dim3(1), dim3(256), 0, stream,
                       pTrue, pGemm, out);
}